// Round 2
// baseline (7594.769 us; speedup 1.0000x reference)
//
#include <hip/hip_runtime.h>

// ---------------------------------------------------------------------------
// Encoder_1030792151055: 2-layer "bidirectional" (both dirs scan forward) LSTM
// B=4096, H=256, SEQ=24, input = one-hot(361).
// 256 persistent WGs x 512 threads; each WG owns 16 batch rows for all 24
// steps. h-state in LDS (fp16), c-state in regs (fp32). Matmuls via
// mfma_f32_16x16x32_f16 with weights pre-packed into fragment-linear fp16.
// One-hot x @ Wih0^T is a gather from a transposed bias-folded table.
// Input/output float dtype (fp32 vs bf16) is SNIFFED on device from Wih0's
// bit patterns (flag in ws), so both harness dtype policies work.
// ---------------------------------------------------------------------------

typedef _Float16 f16x8 __attribute__((ext_vector_type(8)));
typedef float f32x4 __attribute__((ext_vector_type(4)));

#define NB 4096
#define SEQ 24

__device__ __forceinline__ float bf2f(unsigned short u) {
  return __uint_as_float(((unsigned)u) << 16);
}
__device__ __forceinline__ unsigned short f2bf(float f) {
  unsigned x = __float_as_uint(f);
  x += 0x7fffu + ((x >> 16) & 1u);
  return (unsigned short)(x >> 16);
}
__device__ __forceinline__ float ldw(const void* p, size_t i, int isf32) {
  return isf32 ? ((const float*)p)[i] : bf2f(((const unsigned short*)p)[i]);
}
__device__ __forceinline__ float fsig(float x) {
  return __builtin_amdgcn_rcpf(1.f + __expf(-x));
}
__device__ __forceinline__ float ftanh(float x) {
  float ax = __builtin_fabsf(x);
  float z = __expf(-2.f * ax);
  float r = (1.f - z) * __builtin_amdgcn_rcpf(1.f + z);
  return __builtin_copysignf(r, x);
}

// ---- dtype sniff: fp32 buffers' even ushorts are random mantissa bits ----
__global__ void k_sniff(const unsigned short* __restrict__ w, int* flag) {
  unsigned short u = w[threadIdx.x * 2];  // even index: low half if fp32
  int e = (u >> 7) & 0xFF;
  if (e > 123) atomicOr(flag, 1);  // bf16 weights have |w|<=1/16 -> exp<=123
}

// ---- prep: WihT0b[d][p][n] = (p<361 ? Wih0[d][n][p] : 0) + bih0[d][n] + bhh0[d][n]
__global__ void k_prep_wihT0b(const void* __restrict__ Wih0,
                              const void* __restrict__ bih0,
                              const void* __restrict__ bhh0,
                              const int* __restrict__ flag,
                              _Float16* __restrict__ outp) {
  const int isf32 = *flag;
  int idx = blockIdx.x * 256 + threadIdx.x;
  if (idx >= 2 * 362 * 1024) return;
  int n = idx & 1023;
  int p = (idx >> 10) % 362;
  int d = idx / (362 * 1024);
  float v = ldw(bih0, d * 1024 + n, isf32) + ldw(bhh0, d * 1024 + n, isf32);
  if (p < 361) v += ldw(Wih0, (size_t)(d * 1024 + n) * 361 + p, isf32);
  outp[idx] = (_Float16)v;
}

// ---- prep: Whh0 packed:  idx = ((((d*4+j)*4+g)*4+nt)*8+kk)*512 + lane*8 + jj
__global__ void k_prep_whh0(const void* __restrict__ Whh0,
                            const int* __restrict__ flag,
                            _Float16* __restrict__ outp) {
  const int isf32 = *flag;
  int idx = blockIdx.x * 256 + threadIdx.x;
  if (idx >= 2 * 1024 * 256) return;
  int jj = idx & 7, lane = (idx >> 3) & 63, kk = (idx >> 9) & 7;
  int nt = (idx >> 12) & 3, g = (idx >> 14) & 3, j = (idx >> 16) & 3, d = (idx >> 18) & 1;
  int row = g * 256 + j * 64 + nt * 16 + (lane & 15);
  int k = kk * 32 + (lane >> 4) * 8 + jj;
  outp[idx] = (_Float16)ldw(Whh0, (size_t)(d * 1024 + row) * 256 + k, isf32);
}

// ---- prep: [Wih1|Whh1] packed: idx = (((((d*4+j)*4+g)*4+nt)*3+kc)*8+kk)*512 + lane*8 + jj
__global__ void k_prep_w1(const void* __restrict__ Wih1,
                          const void* __restrict__ Whh1,
                          const int* __restrict__ flag,
                          _Float16* __restrict__ outp) {
  const int isf32 = *flag;
  int idx = blockIdx.x * 256 + threadIdx.x;
  if (idx >= 2 * 1024 * 768) return;
  int jj = idx & 7, lane = (idx >> 3) & 63, kk = (idx >> 9) & 7;
  int rest = idx >> 12;
  int kc = rest % 3; rest /= 3;
  int nt = rest & 3; rest >>= 2;
  int g = rest & 3; rest >>= 2;
  int j = rest & 3; int d = rest >> 2;
  int row = g * 256 + j * 64 + nt * 16 + (lane & 15);
  int k = kc * 256 + kk * 32 + (lane >> 4) * 8 + jj;
  float v = (k < 512) ? ldw(Wih1, (size_t)(d * 1024 + row) * 512 + k, isf32)
                      : ldw(Whh1, (size_t)(d * 1024 + row) * 256 + (k - 512), isf32);
  outp[idx] = (_Float16)v;
}

__global__ void k_prep_bias1(const void* __restrict__ bih1,
                             const void* __restrict__ bhh1,
                             const int* __restrict__ flag,
                             float* __restrict__ outp) {
  const int isf32 = *flag;
  int idx = blockIdx.x * 256 + threadIdx.x;
  if (idx >= 2048) return;
  outp[idx] = ldw(bih1, idx, isf32) + ldw(bhh1, idx, isf32);
}

// ---------------------------------------------------------------------------
__global__ __launch_bounds__(512) void lstm_main(
    const int* __restrict__ data,             // [B][24]
    const void* __restrict__ h0,              // [4][B][256]
    const void* __restrict__ c0,              // [4][B][256]
    const _Float16* __restrict__ wihT0b,      // [2][362][1024]
    const _Float16* __restrict__ whh0p,       // packed
    const _Float16* __restrict__ w1p,         // packed
    const float* __restrict__ bias1,          // [2][1024]
    const int* __restrict__ flag,
    void* __restrict__ out) {                 // [B][24][512]
  const int isf32 = *flag;
  const int tid = threadIdx.x;
  const int lane = tid & 63;
  const int w = tid >> 6;       // wave 0..7
  const int d = w >> 2;         // direction / cell
  const int j = w & 3;          // 64-wide hidden slice
  const int n16 = lane & 15;    // col within 16-tile (also A-row m)
  const int q = lane >> 4;
  const int rbase = blockIdx.x * 16;

  __shared__ __align__(16) _Float16 INP[2][16][520];    // [buf][row][2*256 + pad]
  __shared__ __align__(16) _Float16 H1s[2][2][16][264]; // [buf][d][row][256 + pad]

  // init LDS h-state (buffer 0)
  for (int idx = tid; idx < 16 * 512; idx += 512) {
    int r = idx >> 9, c = idx & 511;
    int dd = c >> 8, hh = c & 255;
    INP[0][r][c] = (_Float16)ldw(h0, ((size_t)dd * NB + (rbase + r)) * 256 + hh, isf32);
    H1s[0][dd][r][hh] = (_Float16)ldw(h0, ((size_t)(2 + dd) * NB + (rbase + r)) * 256 + hh, isf32);
  }
  // c-state in regs: [nt][rr] -> row rbase+q*4+rr, col j*64+nt*16+n16
  float c0r[4][4], c1r[4][4];
#pragma unroll
  for (int nt = 0; nt < 4; ++nt)
#pragma unroll
    for (int rr = 0; rr < 4; ++rr) {
      int row = rbase + q * 4 + rr;
      int col = j * 64 + nt * 16 + n16;
      c0r[nt][rr] = ldw(c0, ((size_t)d * NB + row) * 256 + col, isf32);
      c1r[nt][rr] = ldw(c0, ((size_t)(2 + d) * NB + row) * 256 + col, isf32);
    }
  __syncthreads();

  const _Float16* bptr0 = whh0p + (size_t)(d * 4 + j) * (4 * 4 * 8 * 512);
  const _Float16* bptr1 = w1p + (size_t)(d * 4 + j) * (4 * 4 * 3 * 8 * 512);

  for (int t = 0; t < SEQ; ++t) {
    const int prv = t & 1, cur = prv ^ 1;

    // --- layer 0: acc init = gather(one-hot col) + bias (folded in table) ---
    int pos[4];
#pragma unroll
    for (int rr = 0; rr < 4; ++rr) {
      int p = data[(rbase + q * 4 + rr) * SEQ + t];
      pos[rr] = (p < 0) ? 361 : p;
    }
    f32x4 acc[4][4];
#pragma unroll
    for (int g = 0; g < 4; ++g)
#pragma unroll
      for (int nt = 0; nt < 4; ++nt) {
        int col = g * 256 + j * 64 + nt * 16 + n16;
#pragma unroll
        for (int rr = 0; rr < 4; ++rr)
          acc[g][nt][rr] = (float)wihT0b[(size_t)(d * 362 + pos[rr]) * 1024 + col];
      }
    // A fragments: h_l0_d from INP[prv], cols d*256..
    f16x8 a[8];
#pragma unroll
    for (int kk = 0; kk < 8; ++kk)
      a[kk] = *(const f16x8*)&INP[prv][n16][d * 256 + kk * 32 + q * 8];
    // B stream + MFMA
#pragma unroll
    for (int g = 0; g < 4; ++g)
#pragma unroll
      for (int nt = 0; nt < 4; ++nt) {
        f16x8 bf[8];
#pragma unroll
        for (int kk = 0; kk < 8; ++kk)
          bf[kk] = *(const f16x8*)&bptr0[(size_t)(((g * 4 + nt) * 8 + kk) * 512 + lane * 8)];
#pragma unroll
        for (int kk = 0; kk < 8; ++kk)
          acc[g][nt] = __builtin_amdgcn_mfma_f32_16x16x32_f16(a[kk], bf[kk], acc[g][nt], 0, 0, 0);
      }
    // activations -> h' into INP[cur]
#pragma unroll
    for (int nt = 0; nt < 4; ++nt)
#pragma unroll
      for (int rr = 0; rr < 4; ++rr) {
        float iv = fsig(acc[0][nt][rr]);
        float fv = fsig(acc[1][nt][rr]);
        float gv = ftanh(acc[2][nt][rr]);
        float ov = fsig(acc[3][nt][rr]);
        float cn = fv * c0r[nt][rr] + iv * gv;
        c0r[nt][rr] = cn;
        float hn = ov * ftanh(cn);
        INP[cur][q * 4 + rr][d * 256 + j * 64 + nt * 16 + n16] = (_Float16)hn;
      }
    __syncthreads();  // l1 needs all waves' INP[cur]

    // --- layer 1 ---
#pragma unroll
    for (int g = 0; g < 4; ++g)
#pragma unroll
      for (int nt = 0; nt < 4; ++nt) {
        float bv = bias1[d * 1024 + g * 256 + j * 64 + nt * 16 + n16];
        f32x4 b4 = {bv, bv, bv, bv};
        acc[g][nt] = b4;
      }
#pragma unroll
    for (int kc = 0; kc < 3; ++kc) {
      f16x8 a1[8];
#pragma unroll
      for (int kk = 0; kk < 8; ++kk) {
        if (kc < 2)
          a1[kk] = *(const f16x8*)&INP[cur][n16][kc * 256 + kk * 32 + q * 8];
        else
          a1[kk] = *(const f16x8*)&H1s[prv][d][n16][kk * 32 + q * 8];
      }
#pragma unroll
      for (int g = 0; g < 4; ++g)
#pragma unroll
        for (int nt = 0; nt < 4; ++nt) {
          f16x8 bf[8];
#pragma unroll
          for (int kk = 0; kk < 8; ++kk)
            bf[kk] = *(const f16x8*)&bptr1[(size_t)((((g * 4 + nt) * 3 + kc) * 8 + kk) * 512 + lane * 8)];
#pragma unroll
          for (int kk = 0; kk < 8; ++kk)
            acc[g][nt] = __builtin_amdgcn_mfma_f32_16x16x32_f16(a1[kk], bf[kk], acc[g][nt], 0, 0, 0);
        }
    }
    // activations -> h' into H1s[cur] + output
#pragma unroll
    for (int nt = 0; nt < 4; ++nt)
#pragma unroll
      for (int rr = 0; rr < 4; ++rr) {
        float iv = fsig(acc[0][nt][rr]);
        float fv = fsig(acc[1][nt][rr]);
        float gv = ftanh(acc[2][nt][rr]);
        float ov = fsig(acc[3][nt][rr]);
        float cn = fv * c1r[nt][rr] + iv * gv;
        c1r[nt][rr] = cn;
        float hn = ov * ftanh(cn);
        H1s[cur][d][q * 4 + rr][j * 64 + nt * 16 + n16] = (_Float16)hn;
        size_t oi = ((size_t)(rbase + q * 4 + rr) * SEQ + t) * 512 + d * 256 + j * 64 + nt * 16 + n16;
        if (isf32) ((float*)out)[oi] = hn;
        else       ((unsigned short*)out)[oi] = f2bf(hn);
      }
    // no second barrier needed: next step's writes touch the other buffers and
    // are ordered behind this step's barrier for every reader/writer pair.
  }
}

// ---------------------------------------------------------------------------
extern "C" void kernel_launch(void* const* d_in, const int* in_sizes, int n_in,
                              void* d_out, int out_size, void* d_ws, size_t ws_size,
                              hipStream_t stream) {
  const int* data = (const int*)d_in[0];
  const void* h0 = d_in[1];
  const void* c0 = d_in[2];
  const void* Wih0 = d_in[3];
  const void* Whh0 = d_in[4];
  const void* bih0 = d_in[5];
  const void* bhh0 = d_in[6];
  const void* Wih1 = d_in[7];
  const void* Whh1 = d_in[8];
  const void* bih1 = d_in[9];
  const void* bhh1 = d_in[10];

  char* ws = (char*)d_ws;
  _Float16* wihT0b = (_Float16*)ws;                               // 1,482,752 B
  _Float16* whh0p = (_Float16*)(ws + 1482752);                    // 1,048,576 B
  _Float16* w1p = (_Float16*)(ws + 1482752 + 1048576);            // 3,145,728 B
  float* b1 = (float*)(ws + 1482752 + 1048576 + 3145728);         //     8,192 B
  int* flag = (int*)(ws + 1482752 + 1048576 + 3145728 + 8192);    //         4 B

  hipMemsetAsync(flag, 0, 4, stream);
  k_sniff<<<1, 256, 0, stream>>>((const unsigned short*)Wih0, flag);
  k_prep_wihT0b<<<(2 * 362 * 1024 + 255) / 256, 256, 0, stream>>>(Wih0, bih0, bhh0, flag, wihT0b);
  k_prep_whh0<<<(2 * 1024 * 256 + 255) / 256, 256, 0, stream>>>(Whh0, flag, whh0p);
  k_prep_w1<<<(2 * 1024 * 768 + 255) / 256, 256, 0, stream>>>(Wih1, Whh1, flag, w1p);
  k_prep_bias1<<<(2048 + 255) / 256, 256, 0, stream>>>(bih1, bhh1, flag, b1);

  lstm_main<<<256, 512, 0, stream>>>(data, h0, c0, wihT0b, whh0p, w1p, b1, flag, (void*)d_out);
}